// Round 1
// baseline (186.745 us; speedup 1.0000x reference)
//
#include <hip/hip_runtime.h>
#include <hip/hip_bf16.h>
#include <math.h>
#include <stdint.h>

// ---------------------------------------------------------------------------
// MultiSimilarityLoss on MI355X.
//   x: [B=4096, D=1024] fp32 (L2-normalized rows), labels: [B] int32
//   out: scalar fp32 = mean over rows of mined multi-similarity loss
// Pipeline:
//   K1: x fp32 -> bf16 (ws)
//   K2: sim = x_bf16 @ x_bf16^T  (fp32, ws)   -- 128x128 tile MFMA GEMM
//   K3: per-row mining + loss, atomicAdd into out
// ---------------------------------------------------------------------------

#define THRESH    0.5f
#define MARGIN    0.1f
#define SCALE_POS 2.0f
#define SCALE_NEG 40.0f
#define POS_CAP   (1.0f - 1e-5f)

typedef __bf16 bf16x8 __attribute__((ext_vector_type(8)));
typedef float  f32x4  __attribute__((ext_vector_type(4)));

// ---- fp32 -> bf16 (RNE) ----------------------------------------------------
__device__ __forceinline__ uint16_t f2bf(float f) {
  union { float f; uint32_t u; } v; v.f = f;
  uint32_t u = v.u;
  u += 0x7FFFu + ((u >> 16) & 1u);
  return (uint16_t)(u >> 16);
}

__global__ __launch_bounds__(256) void cvt_bf16_kernel(
    const float* __restrict__ x, uint16_t* __restrict__ y, int n) {
  int i = (blockIdx.x * 256 + threadIdx.x) * 4;
  if (i + 3 < n) {
    float4 v = *(const float4*)(x + i);
    ushort4 o;
    o.x = f2bf(v.x); o.y = f2bf(v.y); o.z = f2bf(v.z); o.w = f2bf(v.w);
    *(ushort4*)(y + i) = o;
  }
}

// ---- async global->LDS staging (16B / lane) --------------------------------
#if defined(__has_builtin)
#if __has_builtin(__builtin_amdgcn_global_load_lds)
#define HAVE_GLL 1
#endif
#endif

__device__ __forceinline__ void stage16(const uint16_t* g, uint16_t* lds_wave_base, int lane) {
#ifdef HAVE_GLL
  // HW dest = wave-uniform base + lane*16B; pass the uniform base.
  __builtin_amdgcn_global_load_lds(
      (const __attribute__((address_space(1))) void*)g,
      (__attribute__((address_space(3))) void*)lds_wave_base, 16, 0, 0);
#else
  *(uint4*)(lds_wave_base + lane * 8) = *(const uint4*)g;
#endif
}

// ---- sim = X @ X^T, 128x128 tile, BK=32, 4 waves (2x2), 4x4 16x16x32 MFMAs -
__global__ __launch_bounds__(256) void simgemm_kernel(
    const uint16_t* __restrict__ X, float* __restrict__ C, int B, int D) {
  __shared__ __align__(16) uint16_t sA[128 * 32];
  __shared__ __align__(16) uint16_t sB[128 * 32];

  const int tid  = threadIdx.x;
  const int wave = tid >> 6;
  const int lane = tid & 63;
  const int waveM = wave >> 1, waveN = wave & 1;
  const int bm = blockIdx.x * 128;
  const int bn = blockIdx.y * 128;

  // staging chunk ids (16B chunks; A/B tiles are [128][32] bf16 row-major = 512 chunks)
  const int ch0 = tid;          // chunks 0..255
  const int ch1 = tid + 256;    // chunks 256..511
  const int r0 = ch0 >> 2, c0 = (ch0 & 3) * 8;
  const int r1 = ch1 >> 2, c1 = (ch1 & 3) * 8;

  const uint16_t* gA = X + (size_t)bm * D;
  const uint16_t* gB = X + (size_t)bn * D;

  // wave-uniform LDS bases (chunk ch0 = wave*64 + lane; ch1 = 256 + wave*64 + lane)
  uint16_t* lA0 = sA + wave * 512;
  uint16_t* lA1 = sA + 2048 + wave * 512;
  uint16_t* lB0 = sB + wave * 512;
  uint16_t* lB1 = sB + 2048 + wave * 512;

  // fragment read offsets: lane holds A[m=lane&15][k=(lane>>4)*8 + j]
  const int fr = lane & 15;
  const int fq = lane >> 4;
  const int aoff = (waveM * 64 + fr) * 32 + fq * 8;
  const int boff = (waveN * 64 + fr) * 32 + fq * 8;

  f32x4 acc[4][4] = {};

  for (int k0 = 0; k0 < D; k0 += 32) {
    stage16(gA + (size_t)r0 * D + k0 + c0, lA0, lane);
    stage16(gA + (size_t)r1 * D + k0 + c1, lA1, lane);
    stage16(gB + (size_t)r0 * D + k0 + c0, lB0, lane);
    stage16(gB + (size_t)r1 * D + k0 + c1, lB1, lane);
    __syncthreads();

    bf16x8 af[4], bfv[4];
#pragma unroll
    for (int t = 0; t < 4; ++t) af[t]  = *(const bf16x8*)(sA + aoff + t * 512);
#pragma unroll
    for (int t = 0; t < 4; ++t) bfv[t] = *(const bf16x8*)(sB + boff + t * 512);

#pragma unroll
    for (int mt = 0; mt < 4; ++mt)
#pragma unroll
      for (int nt = 0; nt < 4; ++nt)
        acc[mt][nt] = __builtin_amdgcn_mfma_f32_16x16x32_bf16(
            af[mt], bfv[nt], acc[mt][nt], 0, 0, 0);
    __syncthreads();
  }

  // epilogue: C/D layout col=lane&15, row=(lane>>4)*4+reg
#pragma unroll
  for (int mt = 0; mt < 4; ++mt) {
#pragma unroll
    for (int nt = 0; nt < 4; ++nt) {
      const int col = bn + waveN * 64 + nt * 16 + fr;
#pragma unroll
      for (int r = 0; r < 4; ++r) {
        const int row = bm + waveM * 64 + mt * 16 + fq * 4 + r;
        C[(size_t)row * B + col] = acc[mt][nt][r];
      }
    }
  }
}

// ---- per-row mining + loss -------------------------------------------------
// one block (256 threads) per row; B/256 = 16 sims per thread, stashed in regs.
__global__ __launch_bounds__(256) void rowloss_kernel(
    const float* __restrict__ sim, const int* __restrict__ labels,
    float* __restrict__ out, int B) {
  const int i    = blockIdx.x;
  const int tid  = threadIdx.x;
  const int wave = tid >> 6;
  const int lane = tid & 63;
  const int li   = labels[i];
  const float* row = sim + (size_t)i * B;

  float sv[16];
  unsigned smask = 0;  // bit idx: labels[j]==li
  float minpos = __builtin_inff();
  float maxneg = -__builtin_inff();

  const int iters = B >> 10;  // elements per thread / 4 (float4 each iter)
  for (int it = 0; it < iters; ++it) {
    const int j = it * 1024 + tid * 4;
    float4 v = *(const float4*)(row + j);
    float s4[4] = {v.x, v.y, v.z, v.w};
#pragma unroll
    for (int q = 0; q < 4; ++q) {
      const int jj  = j + q;
      const int idx = it * 4 + q;
      const float s = s4[q];
      sv[idx] = s;
      if (labels[jj] == li) {
        smask |= (1u << idx);
        if (jj != i && s < POS_CAP) minpos = fminf(minpos, s);
      } else {
        maxneg = fmaxf(maxneg, s);
      }
    }
  }

  // block reduce min/max
  __shared__ float red[8];
#pragma unroll
  for (int m = 32; m > 0; m >>= 1) {
    minpos = fminf(minpos, __shfl_xor(minpos, m, 64));
    maxneg = fmaxf(maxneg, __shfl_xor(maxneg, m, 64));
  }
  if (lane == 0) { red[wave] = minpos; red[4 + wave] = maxneg; }
  __syncthreads();
  minpos = fminf(fminf(red[0], red[1]), fminf(red[2], red[3]));
  maxneg = fmaxf(fmaxf(red[4], red[5]), fmaxf(red[6], red[7]));
  __syncthreads();

  // pass 2: mined exp-sums
  float psum = 0.f, nsum = 0.f;
  for (int it = 0; it < iters; ++it) {
#pragma unroll
    for (int q = 0; q < 4; ++q) {
      const int idx = it * 4 + q;
      const int jj  = it * 1024 + tid * 4 + q;
      const float s = sv[idx];
      if ((smask >> idx) & 1u) {
        if (jj != i && s < POS_CAP && (s - MARGIN < maxneg))
          psum += __expf(-SCALE_POS * (s - THRESH));
      } else {
        if (s + MARGIN > minpos)
          nsum += __expf(SCALE_NEG * (s - THRESH));
      }
    }
  }

#pragma unroll
  for (int m = 32; m > 0; m >>= 1) {
    psum += __shfl_xor(psum, m, 64);
    nsum += __shfl_xor(nsum, m, 64);
  }
  if (lane == 0) { red[wave] = psum; red[4 + wave] = nsum; }
  __syncthreads();

  if (tid == 0) {
    psum = red[0] + red[1] + red[2] + red[3];
    nsum = red[4] + red[5] + red[6] + red[7];
    const bool has_row = (minpos != __builtin_inff()) &&
                         (maxneg != -__builtin_inff()) &&
                         (psum > 0.f) && (nsum > 0.f);
    const float loss = has_row
        ? (log1pf(psum) * (1.0f / SCALE_POS) + log1pf(nsum) * (1.0f / SCALE_NEG))
        : 0.f;
    atomicAdd(out, loss * (1.0f / (float)B));
  }
}

// ---------------------------------------------------------------------------
extern "C" void kernel_launch(void* const* d_in, const int* in_sizes, int n_in,
                              void* d_out, int out_size, void* d_ws, size_t ws_size,
                              hipStream_t stream) {
  const float* x      = (const float*)d_in[0];
  const int*   labels = (const int*)d_in[1];
  float*       out    = (float*)d_out;

  const int B = in_sizes[1];           // 4096
  const int D = in_sizes[0] / B;       // 1024

  uint16_t* xbf = (uint16_t*)d_ws;
  size_t xbytes = (((size_t)B * D * 2) + 255) & ~(size_t)255;
  float* sim = (float*)((char*)d_ws + xbytes);

  hipMemsetAsync(d_out, 0, sizeof(float) * out_size, stream);

  const int n = B * D;
  cvt_bf16_kernel<<<n / 1024, 256, 0, stream>>>(x, xbf, n);

  dim3 grid(B / 128, B / 128);
  simgemm_kernel<<<grid, 256, 0, stream>>>(xbf, sim, B, D);

  rowloss_kernel<<<B, 256, 0, stream>>>(sim, labels, out, B);
}

// Round 2
// 143.426 us; speedup vs baseline: 1.3020x; 1.3020x over previous
//
#include <hip/hip_runtime.h>
#include <hip/hip_bf16.h>
#include <math.h>
#include <stdint.h>

// ---------------------------------------------------------------------------
// MultiSimilarityLoss on MI355X.
//   x: [B=4096, D=1024] fp32 (L2-normalized rows), labels: [B] int32
//   out: scalar fp32 = mean over rows of mined multi-similarity loss
// Pipeline:
//   K1: x fp32 -> bf16 (ws)
//   K2: sim = x_bf16 @ x_bf16^T  (fp32, ws)   -- 128x128 tile MFMA GEMM
//   K3: per-row mining + loss -> rowbuf[i]  (NO same-address atomics)
//   K4: reduce rowbuf -> out[0]
// R1 post-mortem: rowloss was 68us, latency-bound (VALUBusy 20%, VGPR=20).
//   Cause: 4096 same-address atomicAdds serializing at L2 + compiler
//   discarding the sv[16] stash. Fix: per-row store + final reduce; labels
//   staged in LDS; pass-2 reloads row from L2/L3 explicitly.
// ---------------------------------------------------------------------------

#define THRESH    0.5f
#define MARGIN    0.1f
#define SCALE_POS 2.0f
#define SCALE_NEG 40.0f
#define POS_CAP   (1.0f - 1e-5f)

typedef __bf16 bf16x8 __attribute__((ext_vector_type(8)));
typedef float  f32x4  __attribute__((ext_vector_type(4)));

// ---- fp32 -> bf16 (RNE) ----------------------------------------------------
__device__ __forceinline__ uint16_t f2bf(float f) {
  union { float f; uint32_t u; } v; v.f = f;
  uint32_t u = v.u;
  u += 0x7FFFu + ((u >> 16) & 1u);
  return (uint16_t)(u >> 16);
}

__global__ __launch_bounds__(256) void cvt_bf16_kernel(
    const float* __restrict__ x, uint16_t* __restrict__ y, int n) {
  int i = (blockIdx.x * 256 + threadIdx.x) * 4;
  if (i + 3 < n) {
    float4 v = *(const float4*)(x + i);
    ushort4 o;
    o.x = f2bf(v.x); o.y = f2bf(v.y); o.z = f2bf(v.z); o.w = f2bf(v.w);
    *(ushort4*)(y + i) = o;
  }
}

// ---- async global->LDS staging (16B / lane) --------------------------------
#if defined(__has_builtin)
#if __has_builtin(__builtin_amdgcn_global_load_lds)
#define HAVE_GLL 1
#endif
#endif

__device__ __forceinline__ void stage16(const uint16_t* g, uint16_t* lds_wave_base, int lane) {
#ifdef HAVE_GLL
  __builtin_amdgcn_global_load_lds(
      (const __attribute__((address_space(1))) void*)g,
      (__attribute__((address_space(3))) void*)lds_wave_base, 16, 0, 0);
#else
  *(uint4*)(lds_wave_base + lane * 8) = *(const uint4*)g;
#endif
}

// ---- sim = X @ X^T, 128x128 tile, BK=32, 4 waves (2x2), 4x4 16x16x32 MFMAs -
__global__ __launch_bounds__(256) void simgemm_kernel(
    const uint16_t* __restrict__ X, float* __restrict__ C, int B, int D) {
  __shared__ __align__(16) uint16_t sA[128 * 32];
  __shared__ __align__(16) uint16_t sB[128 * 32];

  const int tid  = threadIdx.x;
  const int wave = tid >> 6;
  const int lane = tid & 63;
  const int waveM = wave >> 1, waveN = wave & 1;
  const int bm = blockIdx.x * 128;
  const int bn = blockIdx.y * 128;

  const int ch0 = tid;
  const int ch1 = tid + 256;
  const int r0 = ch0 >> 2, c0 = (ch0 & 3) * 8;
  const int r1 = ch1 >> 2, c1 = (ch1 & 3) * 8;

  const uint16_t* gA = X + (size_t)bm * D;
  const uint16_t* gB = X + (size_t)bn * D;

  uint16_t* lA0 = sA + wave * 512;
  uint16_t* lA1 = sA + 2048 + wave * 512;
  uint16_t* lB0 = sB + wave * 512;
  uint16_t* lB1 = sB + 2048 + wave * 512;

  const int fr = lane & 15;
  const int fq = lane >> 4;
  const int aoff = (waveM * 64 + fr) * 32 + fq * 8;
  const int boff = (waveN * 64 + fr) * 32 + fq * 8;

  f32x4 acc[4][4] = {};

  for (int k0 = 0; k0 < D; k0 += 32) {
    stage16(gA + (size_t)r0 * D + k0 + c0, lA0, lane);
    stage16(gA + (size_t)r1 * D + k0 + c1, lA1, lane);
    stage16(gB + (size_t)r0 * D + k0 + c0, lB0, lane);
    stage16(gB + (size_t)r1 * D + k0 + c1, lB1, lane);
    __syncthreads();

    bf16x8 af[4], bfv[4];
#pragma unroll
    for (int t = 0; t < 4; ++t) af[t]  = *(const bf16x8*)(sA + aoff + t * 512);
#pragma unroll
    for (int t = 0; t < 4; ++t) bfv[t] = *(const bf16x8*)(sB + boff + t * 512);

#pragma unroll
    for (int mt = 0; mt < 4; ++mt)
#pragma unroll
      for (int nt = 0; nt < 4; ++nt)
        acc[mt][nt] = __builtin_amdgcn_mfma_f32_16x16x32_bf16(
            af[mt], bfv[nt], acc[mt][nt], 0, 0, 0);
    __syncthreads();
  }

#pragma unroll
  for (int mt = 0; mt < 4; ++mt) {
#pragma unroll
    for (int nt = 0; nt < 4; ++nt) {
      const int col = bn + waveN * 64 + nt * 16 + fr;
#pragma unroll
      for (int r = 0; r < 4; ++r) {
        const int row = bm + waveM * 64 + mt * 16 + fq * 4 + r;
        C[(size_t)row * B + col] = acc[mt][nt][r];
      }
    }
  }
}

// ---- per-row mining + loss -------------------------------------------------
// one block (256 threads) per row. Labels staged in LDS. Two passes over the
// row; pass 2 reloads from L2/L3 (explicitly, instead of hoping for a
// register stash the compiler won't keep). Plain store per row, no atomics.
__global__ __launch_bounds__(256) void rowloss_kernel(
    const float* __restrict__ sim, const int* __restrict__ labels,
    float* __restrict__ rowbuf, int B) {
  __shared__ int   slab[4096];
  __shared__ float red[8];

  const int i    = blockIdx.x;
  const int tid  = threadIdx.x;
  const int wave = tid >> 6;
  const int lane = tid & 63;
  const float* row = sim + (size_t)i * B;

  // stage labels into LDS (B ints)
  for (int t = tid; t < (B >> 2); t += 256)
    ((int4*)slab)[t] = ((const int4*)labels)[t];
  __syncthreads();

  const int li = slab[i];

  float minpos = __builtin_inff();
  float maxneg = -__builtin_inff();

  const int iters = B >> 10;  // float4 per thread per pass
  for (int it = 0; it < iters; ++it) {
    const int j = it * 1024 + tid * 4;
    float4 v = *(const float4*)(row + j);
    float s4[4] = {v.x, v.y, v.z, v.w};
#pragma unroll
    for (int q = 0; q < 4; ++q) {
      const int jj = j + q;
      const float s = s4[q];
      if (slab[jj] == li) {
        if (jj != i && s < POS_CAP) minpos = fminf(minpos, s);
      } else {
        maxneg = fmaxf(maxneg, s);
      }
    }
  }

#pragma unroll
  for (int m = 32; m > 0; m >>= 1) {
    minpos = fminf(minpos, __shfl_xor(minpos, m, 64));
    maxneg = fmaxf(maxneg, __shfl_xor(maxneg, m, 64));
  }
  if (lane == 0) { red[wave] = minpos; red[4 + wave] = maxneg; }
  __syncthreads();
  minpos = fminf(fminf(red[0], red[1]), fminf(red[2], red[3]));
  maxneg = fmaxf(fmaxf(red[4], red[5]), fmaxf(red[6], red[7]));
  __syncthreads();

  // pass 2: mined exp-sums (row reload hits L2/L3)
  float psum = 0.f, nsum = 0.f;
  for (int it = 0; it < iters; ++it) {
    const int j = it * 1024 + tid * 4;
    float4 v = *(const float4*)(row + j);
    float s4[4] = {v.x, v.y, v.z, v.w};
#pragma unroll
    for (int q = 0; q < 4; ++q) {
      const int jj = j + q;
      const float s = s4[q];
      if (slab[jj] == li) {
        if (jj != i && s < POS_CAP && (s - MARGIN < maxneg))
          psum += __expf(-SCALE_POS * (s - THRESH));
      } else {
        if (s + MARGIN > minpos)
          nsum += __expf(SCALE_NEG * (s - THRESH));
      }
    }
  }

#pragma unroll
  for (int m = 32; m > 0; m >>= 1) {
    psum += __shfl_xor(psum, m, 64);
    nsum += __shfl_xor(nsum, m, 64);
  }
  if (lane == 0) { red[wave] = psum; red[4 + wave] = nsum; }
  __syncthreads();

  if (tid == 0) {
    psum = red[0] + red[1] + red[2] + red[3];
    nsum = red[4] + red[5] + red[6] + red[7];
    const bool has_row = (minpos != __builtin_inff()) &&
                         (maxneg != -__builtin_inff()) &&
                         (psum > 0.f) && (nsum > 0.f);
    rowbuf[i] = has_row
        ? (log1pf(psum) * (1.0f / SCALE_POS) + log1pf(nsum) * (1.0f / SCALE_NEG))
        : 0.f;
  }
}

// ---- final reduction: 4096 floats -> out[0] --------------------------------
__global__ __launch_bounds__(256) void finalreduce_kernel(
    const float* __restrict__ rowbuf, float* __restrict__ out, int B) {
  __shared__ float red[4];
  const int tid  = threadIdx.x;
  const int wave = tid >> 6;
  const int lane = tid & 63;

  float s = 0.f;
  for (int j = tid * 4; j < B; j += 1024) {
    float4 v = *(const float4*)(rowbuf + j);
    s += v.x + v.y + v.z + v.w;
  }
#pragma unroll
  for (int m = 32; m > 0; m >>= 1) s += __shfl_xor(s, m, 64);
  if (lane == 0) red[wave] = s;
  __syncthreads();
  if (tid == 0)
    out[0] = (red[0] + red[1] + red[2] + red[3]) * (1.0f / (float)B);
}

// ---------------------------------------------------------------------------
extern "C" void kernel_launch(void* const* d_in, const int* in_sizes, int n_in,
                              void* d_out, int out_size, void* d_ws, size_t ws_size,
                              hipStream_t stream) {
  const float* x      = (const float*)d_in[0];
  const int*   labels = (const int*)d_in[1];
  float*       out    = (float*)d_out;

  const int B = in_sizes[1];           // 4096
  const int D = in_sizes[0] / B;       // 1024

  uint16_t* xbf = (uint16_t*)d_ws;
  size_t xbytes = (((size_t)B * D * 2) + 255) & ~(size_t)255;
  float* sim = (float*)((char*)d_ws + xbytes);
  size_t simbytes = (size_t)B * B * 4;
  float* rowbuf = (float*)((char*)d_ws + xbytes + simbytes);

  const int n = B * D;
  cvt_bf16_kernel<<<n / 1024, 256, 0, stream>>>(x, xbf, n);

  dim3 grid(B / 128, B / 128);
  simgemm_kernel<<<grid, 256, 0, stream>>>(xbf, sim, B, D);

  rowloss_kernel<<<B, 256, 0, stream>>>(sim, labels, rowbuf, B);
  finalreduce_kernel<<<1, 256, 0, stream>>>(rowbuf, out, B);
}